// Round 1
// baseline (3165.266 us; speedup 1.0000x reference)
//
#include <hip/hip_runtime.h>
#include <cstdint>
#include <cstddef>

typedef __bf16 bf16_t;
typedef __attribute__((ext_vector_type(8))) __bf16 bf16x8;
typedef __attribute__((ext_vector_type(4))) float f32x4;

__device__ __forceinline__ void async_cp16(const void* g, void* l) {
    __builtin_amdgcn_global_load_lds(
        (const __attribute__((address_space(1))) void*)g,
        (__attribute__((address_space(3))) void*)l,
        16, 0, 0);
}

// ---------------- conversion kernels ----------------
__global__ void k_cvt_transpose(const float* __restrict__ src, bf16_t* __restrict__ dst,
                                int K, int N) {
    int idx = blockIdx.x * 256 + threadIdx.x;
    if (idx >= K * N) return;
    int k = idx / N, n = idx - k * N;
    dst[(size_t)n * K + k] = (bf16_t)src[idx];
}

__global__ void k_cvt_flat(const float* __restrict__ src, bf16_t* __restrict__ dst, int n) {
    int idx = blockIdx.x * 256 + threadIdx.x;
    if (idx >= n) return;
    dst[idx] = (bf16_t)src[idx];
}

// wrz: (2048 x 1280) bf16; row n (n<1024: r-gate unit n, n>=1024: z-gate unit n-1024)
// cols 0..255 from Wih[n][c], cols 256..1279 from Whh[n][c-256]. brz[n]=bih[n]+bhh[n].
__global__ void k_build_wrz(const float* __restrict__ Wih, const float* __restrict__ Whh,
                            const float* __restrict__ bih, const float* __restrict__ bhh,
                            bf16_t* __restrict__ wrz, float* __restrict__ brz) {
    int idx = blockIdx.x * 256 + threadIdx.x;
    if (idx >= 2048 * 1280) return;
    int n = idx / 1280, c = idx - n * 1280;
    float v = (c < 256) ? Wih[(size_t)n * 256 + c] : Whh[(size_t)n * 1024 + (c - 256)];
    wrz[idx] = (bf16_t)v;
    if (c == 0) brz[n] = bih[n] + bhh[n];
}

__global__ void k_cvt_x(const float* __restrict__ xt, bf16_t* __restrict__ xh, int B) {
    int idx = blockIdx.x * 256 + threadIdx.x;
    if (idx >= B * 256) return;
    int b = idx >> 8, c = idx & 255;
    xh[(size_t)b * 1280 + c] = (bf16_t)xt[idx];
}

__global__ void k_cvt_h0(const float* __restrict__ state, bf16_t* __restrict__ hbf, int B) {
    int idx = blockIdx.x * 256 + threadIdx.x;
    if (idx >= B * 1024) return;
    int b = idx >> 10, j = idx & 1023;
    hbf[idx] = (bf16_t)state[(size_t)b * 1040 + 16 + j];
}

// ---------------- GEMM: C(MxN) = A(MxK) * Bt(NxK)^T, bf16 in, f32 acc ----------------
// 128x128 tile, BK=32, 256 threads (4 waves, 2x2 of 64x64), m97 structure.
enum { EPI_TANH = 0, EPI_RK4 = 1, EPI_SIG = 2, EPI_BIASBF = 3, EPI_FIN = 4 };

template <int EPI, int STAGE>
__global__ __launch_bounds__(256) void gemm_bt(
    const bf16_t* __restrict__ A, int lda,
    const bf16_t* __restrict__ Bt,
    int N, int K,
    const float* __restrict__ bias,
    bf16_t* __restrict__ obf,
    const float* __restrict__ state,
    float* __restrict__ accb,
    float* __restrict__ outp,
    bf16_t* __restrict__ xh_ht,       // = xh + 256 (ld 1280), stage-3 write
    const bf16_t* __restrict__ rz,    // B x 2048 bf16 (FIN)
    const bf16_t* __restrict__ inb)   // B x 1024 bf16 (FIN)
{
    __shared__ __align__(16) bf16_t As[128 * 32];
    __shared__ __align__(16) bf16_t Bs[128 * 32];

    const int tid  = threadIdx.x;
    const int lane = tid & 63;
    const int wv   = tid >> 6;
    const int bm   = blockIdx.y << 7;
    const int bn   = blockIdx.x << 7;
    const int wm   = (wv >> 1) << 6;
    const int wn   = (wv & 1) << 6;

    f32x4 acc[4][4] = {};

    // staging: each wave loads 32 rows of each tile (2 issues x 16 rows x 64B)
    const int srow = (wv << 5) + (lane >> 2);
    const int scol = (lane & 3) << 3;
    const bf16_t* gA = A  + (size_t)(bm + srow) * lda + scol;
    const bf16_t* gB = Bt + (size_t)(bn + srow) * K   + scol;
    bf16_t* lA0 = &As[(wv << 5) * 32];
    bf16_t* lA1 = &As[((wv << 5) + 16) * 32];
    bf16_t* lB0 = &Bs[(wv << 5) * 32];
    bf16_t* lB1 = &Bs[((wv << 5) + 16) * 32];
    const size_t a16 = (size_t)16 * lda;
    const size_t b16 = (size_t)16 * K;

    const int fr = lane & 15;     // fragment row (A) / col (B)
    const int kg = lane >> 4;     // k-group (8 bf16 each)
    const bf16_t* rA = &As[(wm + fr) * 32 + (kg << 3)];
    const bf16_t* rB = &Bs[(wn + fr) * 32 + (kg << 3)];

    for (int k0 = 0; k0 < K; k0 += 32) {
        async_cp16(gA,       lA0);
        async_cp16(gA + a16, lA1);
        async_cp16(gB,       lB0);
        async_cp16(gB + b16, lB1);
        gA += 32; gB += 32;
        __syncthreads();   // compiler drains vmcnt before s_barrier

        bf16x8 af[4], bfr[4];
#pragma unroll
        for (int i = 0; i < 4; ++i) af[i]  = *(const bf16x8*)(rA + i * 16 * 32);
#pragma unroll
        for (int j = 0; j < 4; ++j) bfr[j] = *(const bf16x8*)(rB + j * 16 * 32);
#pragma unroll
        for (int i = 0; i < 4; ++i)
#pragma unroll
            for (int j = 0; j < 4; ++j)
                acc[i][j] = __builtin_amdgcn_mfma_f32_16x16x32_bf16(af[i], bfr[j], acc[i][j], 0, 0, 0);
        __syncthreads();
    }

    // C/D layout (verified m89/m91): col = lane&15, row = (lane>>4)*4 + reg
    const int orow0 = bm + wm + (kg << 2);
    const int ocol0 = bn + wn + fr;
#pragma unroll
    for (int i = 0; i < 4; ++i) {
#pragma unroll
        for (int j = 0; j < 4; ++j) {
#pragma unroll
            for (int r = 0; r < 4; ++r) {
                const int row = orow0 + i * 16 + r;
                const int col = ocol0 + j * 16;
                const float c = acc[i][j][r];
                if constexpr (EPI == EPI_TANH) {
                    obf[(size_t)row * N + col] = (bf16_t)tanhf(c + bias[col]);
                } else if constexpr (EPI == EPI_RK4) {
                    const float kk = c + bias[col];
                    const size_t hidx = ((size_t)row << 10) + col;
                    const float h0 = state[(size_t)row * 1040 + 16 + col];
                    if constexpr (STAGE == 0) {
                        accb[hidx] = kk;
                        obf[hidx] = (bf16_t)(h0 + 0.05f * kk);
                    } else if constexpr (STAGE == 1) {
                        accb[hidx] += 2.f * kk;
                        obf[hidx] = (bf16_t)(h0 + 0.05f * kk);
                    } else if constexpr (STAGE == 2) {
                        accb[hidx] += 2.f * kk;
                        obf[hidx] = (bf16_t)(h0 + 0.1f * kk);
                    } else {
                        const float ht = h0 + (0.1f / 6.f) * (accb[hidx] + kk);
                        outp[(size_t)row * 1040 + 16 + col] = ht;
                        xh_ht[(size_t)row * 1280 + col] = (bf16_t)ht;
                    }
                } else if constexpr (EPI == EPI_SIG) {
                    const float v = c + bias[col];
                    obf[(size_t)row * N + col] = (bf16_t)(1.f / (1.f + expf(-v)));
                } else if constexpr (EPI == EPI_BIASBF) {
                    obf[(size_t)row * N + col] = (bf16_t)(c + bias[col]);
                } else {  // EPI_FIN
                    const float hn  = c + bias[col];
                    const float r_  = (float)rz[((size_t)row << 11) + col];
                    const float z_  = (float)rz[((size_t)row << 11) + 1024 + col];
                    const float inv = (float)inb[((size_t)row << 10) + col];
                    const float nn  = tanhf(inv + r_ * hn);
                    const size_t oidx = (size_t)row * 1040 + 16 + col;
                    const float htv = outp[oidx];
                    outp[oidx] = (1.f - z_) * nn + z_ * htv;
                }
            }
        }
    }
}

// ---------------- readout: out[:, :16] ----------------
__global__ void k_ly(const float* __restrict__ outh, const float* __restrict__ state,
                     const float* __restrict__ Wly, const float* __restrict__ bly,
                     const int* __restrict__ y_type, float* __restrict__ outp, int B) {
    int t = blockIdx.x * 256 + threadIdx.x;
    if (t >= B * 16) return;
    int o = t & 15, b = t >> 4;
    const float* hrow = outh + (size_t)b * 1040 + 16;
    float s = bly[o];
#pragma unroll 8
    for (int k = 0; k < 1024; ++k) s += hrow[k] * Wly[k * 16 + o];
    outp[(size_t)b * 1040 + o] = (y_type[o] == 0) ? s : state[(size_t)b * 1040 + o];
}

// ---------------- launcher ----------------
extern "C" void kernel_launch(void* const* d_in, const int* in_sizes, int n_in,
                              void* d_out, int out_size, void* d_ws, size_t ws_size,
                              hipStream_t stream) {
    const float* state = (const float*)d_in[0];
    const float* xt    = (const float*)d_in[1];
    const float* W1    = (const float*)d_in[2];
    const float* b1    = (const float*)d_in[3];
    const float* W2    = (const float*)d_in[4];
    const float* b2    = (const float*)d_in[5];
    const float* Wih   = (const float*)d_in[6];
    const float* Whh   = (const float*)d_in[7];
    const float* bih   = (const float*)d_in[8];
    const float* bhh   = (const float*)d_in[9];
    const float* Wly   = (const float*)d_in[10];
    const float* bly   = (const float*)d_in[11];
    const int*   y_type = (const int*)d_in[12];
    float* out = (float*)d_out;

    const int B = in_sizes[0] / 1040;   // 32768

    char* ws = (char*)d_ws;
    bf16_t* w1t  = (bf16_t*)(ws);                    // 2048 x 1024
    bf16_t* w2t  = (bf16_t*)(ws + 4194304);          // 1024 x 2048
    bf16_t* wrz  = (bf16_t*)(ws + 8388608);          // 2048 x 1280
    bf16_t* win  = (bf16_t*)(ws + 13631488);         // 1024 x 256
    bf16_t* whn  = (bf16_t*)(ws + 14155776);         // 1024 x 1024
    float*  brz  = (float*) (ws + 16252928);         // 2048
    bf16_t* xh   = (bf16_t*)(ws + 16261120);         // B x 1280 ([x | h_])
    bf16_t* hbf  = (bf16_t*)(ws + 100147200);        // B x 1024 (RK4 stage input)
    bf16_t* T    = (bf16_t*)(ws + 167256064);        // B x 2048 (tanh act; later r/z)
    float*  accb = (float*) (ws + 301473792);        // B x 1024 (k-sum; later i_n bf16)
    bf16_t* inbf = (bf16_t*)accb;

    // weight prep + input casts
    k_cvt_transpose<<<(1024 * 2048) / 256, 256, 0, stream>>>(W1, w1t, 1024, 2048);
    k_cvt_transpose<<<(2048 * 1024) / 256, 256, 0, stream>>>(W2, w2t, 2048, 1024);
    k_build_wrz<<<(2048 * 1280) / 256, 256, 0, stream>>>(Wih, Whh, bih, bhh, wrz, brz);
    k_cvt_flat<<<(1024 * 256) / 256, 256, 0, stream>>>(Wih + 2048 * 256, win, 1024 * 256);
    k_cvt_flat<<<(1024 * 1024) / 256, 256, 0, stream>>>(Whh + 2048 * 1024, whn, 1024 * 1024);
    k_cvt_x<<<(B * 256) / 256, 256, 0, stream>>>(xt, xh, B);
    k_cvt_h0<<<(B * 1024) / 256, 256, 0, stream>>>(state, hbf, B);

    const dim3 blk(256);
    const int MB = B / 128;   // 256 m-tiles

    // ---- RK4: 4 stages of (tanh GEMM) -> (W2 GEMM + stage epilogue) ----
    gemm_bt<EPI_TANH, 0><<<dim3(16, MB), blk, 0, stream>>>(hbf, 1024, w1t, 2048, 1024, b1, T,
        nullptr, nullptr, nullptr, nullptr, nullptr, nullptr);
    gemm_bt<EPI_RK4, 0><<<dim3(8, MB), blk, 0, stream>>>(T, 2048, w2t, 1024, 2048, b2, hbf,
        state, accb, out, xh + 256, nullptr, nullptr);

    gemm_bt<EPI_TANH, 0><<<dim3(16, MB), blk, 0, stream>>>(hbf, 1024, w1t, 2048, 1024, b1, T,
        nullptr, nullptr, nullptr, nullptr, nullptr, nullptr);
    gemm_bt<EPI_RK4, 1><<<dim3(8, MB), blk, 0, stream>>>(T, 2048, w2t, 1024, 2048, b2, hbf,
        state, accb, out, xh + 256, nullptr, nullptr);

    gemm_bt<EPI_TANH, 0><<<dim3(16, MB), blk, 0, stream>>>(hbf, 1024, w1t, 2048, 1024, b1, T,
        nullptr, nullptr, nullptr, nullptr, nullptr, nullptr);
    gemm_bt<EPI_RK4, 2><<<dim3(8, MB), blk, 0, stream>>>(T, 2048, w2t, 1024, 2048, b2, hbf,
        state, accb, out, xh + 256, nullptr, nullptr);

    gemm_bt<EPI_TANH, 0><<<dim3(16, MB), blk, 0, stream>>>(hbf, 1024, w1t, 2048, 1024, b1, T,
        nullptr, nullptr, nullptr, nullptr, nullptr, nullptr);
    gemm_bt<EPI_RK4, 3><<<dim3(8, MB), blk, 0, stream>>>(T, 2048, w2t, 1024, 2048, b2, hbf,
        state, accb, out, xh + 256, nullptr, nullptr);

    // ---- GRU ----
    // r,z gates: [x|h_] (K=1280) @ wrz^T -> sigmoid -> T (B x 2048 bf16)
    gemm_bt<EPI_SIG, 0><<<dim3(16, MB), blk, 0, stream>>>(xh, 1280, wrz, 2048, 1280, brz, T,
        nullptr, nullptr, nullptr, nullptr, nullptr, nullptr);
    // i_n: x (K=256) @ Wih_n^T + bih_n -> bf16 (into accb space)
    gemm_bt<EPI_BIASBF, 0><<<dim3(8, MB), blk, 0, stream>>>(xh, 1280, win, 1024, 256,
        bih + 2048, inbf, nullptr, nullptr, nullptr, nullptr, nullptr, nullptr);
    // h_n GEMM + full GRU merge -> out[:, 16:]
    gemm_bt<EPI_FIN, 0><<<dim3(8, MB), blk, 0, stream>>>(xh + 256, 1280, whn, 1024, 1024,
        bhh + 2048, nullptr, nullptr, nullptr, out, nullptr, T, inbf);

    // ---- readout out[:, :16] ----
    k_ly<<<(B * 16) / 256, 256, 0, stream>>>(out, state, Wly, bly, y_type, out, B);
}

// Round 2
// 2865.877 us; speedup vs baseline: 1.1045x; 1.1045x over previous
//
#include <hip/hip_runtime.h>
#include <cstdint>
#include <cstddef>

typedef __bf16 bf16_t;
typedef __attribute__((ext_vector_type(8))) __bf16 bf16x8;
typedef __attribute__((ext_vector_type(4))) float f32x4;

__device__ __forceinline__ void async_cp16(const void* g, void* l) {
    __builtin_amdgcn_global_load_lds(
        (const __attribute__((address_space(1))) void*)g,
        (__attribute__((address_space(3))) void*)l,
        16, 0, 0);
}

__device__ __forceinline__ float fast_tanh(float x) {
    float ax = fabsf(x);
    float e = __expf(-2.f * ax);
    float t = (1.f - e) / (1.f + e);
    return x < 0.f ? -t : t;
}
__device__ __forceinline__ float fast_sig(float x) {
    return 1.f / (1.f + __expf(-x));
}

// ---------------- conversion kernels ----------------
__global__ void k_cvt_transpose(const float* __restrict__ src, bf16_t* __restrict__ dst,
                                int K, int N) {
    int idx = blockIdx.x * 256 + threadIdx.x;
    if (idx >= K * N) return;
    int k = idx / N, n = idx - k * N;
    dst[(size_t)n * K + k] = (bf16_t)src[idx];
}

__global__ void k_cvt_flat(const float* __restrict__ src, bf16_t* __restrict__ dst, int n) {
    int idx = blockIdx.x * 256 + threadIdx.x;
    if (idx >= n) return;
    dst[idx] = (bf16_t)src[idx];
}

__global__ void k_build_wrz(const float* __restrict__ Wih, const float* __restrict__ Whh,
                            const float* __restrict__ bih, const float* __restrict__ bhh,
                            bf16_t* __restrict__ wrz, float* __restrict__ brz) {
    int idx = blockIdx.x * 256 + threadIdx.x;
    if (idx >= 2048 * 1280) return;
    int n = idx / 1280, c = idx - n * 1280;
    float v = (c < 256) ? Wih[(size_t)n * 256 + c] : Whh[(size_t)n * 1024 + (c - 256)];
    wrz[idx] = (bf16_t)v;
    if (c == 0) brz[n] = bih[n] + bhh[n];
}

__global__ void k_cvt_x(const float* __restrict__ xt, bf16_t* __restrict__ xh, int B) {
    int idx = blockIdx.x * 256 + threadIdx.x;
    if (idx >= B * 256) return;
    int b = idx >> 8, c = idx & 255;
    xh[(size_t)b * 1280 + c] = (bf16_t)xt[idx];
}

__global__ void k_cvt_h0(const float* __restrict__ state, bf16_t* __restrict__ h0b, int B) {
    int idx = blockIdx.x * 256 + threadIdx.x;
    if (idx >= B * 1024) return;
    int b = idx >> 10, j = idx & 1023;
    h0b[idx] = (bf16_t)state[(size_t)b * 1040 + 16 + j];
}

// ---------------- GEMM: C(MxN) = A(MxK) * Bt(NxK)^T, bf16 in, f32 acc ----------------
// 128x128 tile, BK=32, 256 threads (4 waves, 2x2 of 64x64).
// 2-phase double-buffered staging (T3 minimum recipe) + XCD swizzle (T1).
enum { EPI_TANH = 0, EPI_RK4 = 1, EPI_SIG = 2, EPI_BIASBF = 3, EPI_FIN = 4 };

template <int EPI, int STAGE>
__global__ __launch_bounds__(256) void gemm_bt(
    const bf16_t* __restrict__ A, int lda,
    const bf16_t* __restrict__ Bt,
    int N, int K,
    const float* __restrict__ bias,
    bf16_t* __restrict__ obf,
    const bf16_t* __restrict__ h0b,   // B x 1024 bf16 (RK4 stages 0-2)
    const float* __restrict__ state,  // f32, ld 1040 (RK4 stage 3 only)
    bf16_t* __restrict__ kacc,        // B x 1024 bf16 (k-sum)
    float* __restrict__ outp,         // f32 out, ld 1040
    bf16_t* __restrict__ xh_ht,       // = xh + 256 (ld 1280): stage-3 write / FIN ht read
    const bf16_t* __restrict__ rz,    // B x 2048 bf16 (FIN)
    const bf16_t* __restrict__ inb)   // B x 1024 bf16 (FIN)
{
    __shared__ __align__(16) bf16_t As[2 * 128 * 32];
    __shared__ __align__(16) bf16_t Bs[2 * 128 * 32];

    const int tid  = threadIdx.x;
    const int lane = tid & 63;
    const int wv   = tid >> 6;

    // XCD-aware bijective swizzle (all grids here have nwg % 8 == 0)
    const int gx  = gridDim.x;
    int bid = blockIdx.y * gx + blockIdx.x;
    const int nwg = gx * gridDim.y;
    if ((nwg & 7) == 0) {
        bid = (bid & 7) * (nwg >> 3) + (bid >> 3);
    }
    const int bm = (bid / gx) << 7;
    const int bn = (bid % gx) << 7;

    const int wm = (wv >> 1) << 6;
    const int wn = (wv & 1) << 6;

    f32x4 acc[4][4] = {};

    // staging: each wave loads 32 rows of each tile (2 issues x 16 rows x 64B)
    const int srow = (wv << 5) + (lane >> 2);
    const int scol = (lane & 3) << 3;
    const bf16_t* gA = A  + (size_t)(bm + srow) * lda + scol;
    const bf16_t* gB = Bt + (size_t)(bn + srow) * K   + scol;
    const int lA0o = (wv << 5) * 32;
    const int lA1o = ((wv << 5) + 16) * 32;
    const size_t a16 = (size_t)16 * lda;
    const size_t b16 = (size_t)16 * K;

    const int fr = lane & 15;     // fragment row (A) / col (B)
    const int kg = lane >> 4;     // k-group (8 bf16 each)
    const int rAo = (wm + fr) * 32 + (kg << 3);
    const int rBo = (wn + fr) * 32 + (kg << 3);

    // prologue: stage K-tile 0 into buffer 0
    async_cp16(gA,       &As[lA0o]);
    async_cp16(gA + a16, &As[lA1o]);
    async_cp16(gB,       &Bs[lA0o]);
    async_cp16(gB + b16, &Bs[lA1o]);
    gA += 32; gB += 32;

    int cur = 0;
    for (int k0 = 0; k0 < K; k0 += 32) {
        __syncthreads();   // drains vmcnt(0): buf[cur] ready; prior reads of buf[cur^1] done
        if (k0 + 32 < K) {
            const int nb = (cur ^ 1) * 4096;
            async_cp16(gA,       &As[nb + lA0o]);
            async_cp16(gA + a16, &As[nb + lA1o]);
            async_cp16(gB,       &Bs[nb + lA0o]);
            async_cp16(gB + b16, &Bs[nb + lA1o]);
            gA += 32; gB += 32;
        }

        const bf16_t* rA = &As[cur * 4096 + rAo];
        const bf16_t* rB = &Bs[cur * 4096 + rBo];
        bf16x8 af[4], bfr[4];
#pragma unroll
        for (int i = 0; i < 4; ++i) af[i]  = *(const bf16x8*)(rA + i * 16 * 32);
#pragma unroll
        for (int j = 0; j < 4; ++j) bfr[j] = *(const bf16x8*)(rB + j * 16 * 32);
#pragma unroll
        for (int i = 0; i < 4; ++i)
#pragma unroll
            for (int j = 0; j < 4; ++j)
                acc[i][j] = __builtin_amdgcn_mfma_f32_16x16x32_bf16(af[i], bfr[j], acc[i][j], 0, 0, 0);
        cur ^= 1;
    }

    // C/D layout (verified m89/m91): col = lane&15, row = (lane>>4)*4 + reg
    const int orow0 = bm + wm + (kg << 2);
    const int ocol0 = bn + wn + fr;
#pragma unroll
    for (int i = 0; i < 4; ++i) {
#pragma unroll
        for (int j = 0; j < 4; ++j) {
#pragma unroll
            for (int r = 0; r < 4; ++r) {
                const int row = orow0 + i * 16 + r;
                const int col = ocol0 + j * 16;
                const float c = acc[i][j][r];
                if constexpr (EPI == EPI_TANH) {
                    obf[(size_t)row * N + col] = (bf16_t)fast_tanh(c + bias[col]);
                } else if constexpr (EPI == EPI_RK4) {
                    const float kk = c + bias[col];
                    const size_t hidx = ((size_t)row << 10) + col;
                    if constexpr (STAGE == 0) {
                        const float h0 = (float)h0b[hidx];
                        kacc[hidx] = (bf16_t)kk;
                        obf[hidx] = (bf16_t)(h0 + 0.05f * kk);
                    } else if constexpr (STAGE == 1) {
                        const float h0 = (float)h0b[hidx];
                        kacc[hidx] = (bf16_t)((float)kacc[hidx] + 2.f * kk);
                        obf[hidx] = (bf16_t)(h0 + 0.05f * kk);
                    } else if constexpr (STAGE == 2) {
                        const float h0 = (float)h0b[hidx];
                        kacc[hidx] = (bf16_t)((float)kacc[hidx] + 2.f * kk);
                        obf[hidx] = (bf16_t)(h0 + 0.1f * kk);
                    } else {
                        const float h0 = state[(size_t)row * 1040 + 16 + col];
                        const float ht = h0 + (0.1f / 6.f) * ((float)kacc[hidx] + kk);
                        outp[(size_t)row * 1040 + 16 + col] = ht;
                        xh_ht[(size_t)row * 1280 + col] = (bf16_t)ht;
                    }
                } else if constexpr (EPI == EPI_SIG) {
                    obf[(size_t)row * N + col] = (bf16_t)fast_sig(c + bias[col]);
                } else if constexpr (EPI == EPI_BIASBF) {
                    obf[(size_t)row * N + col] = (bf16_t)(c + bias[col]);
                } else {  // EPI_FIN
                    const float hn  = c + bias[col];
                    const float r_  = (float)rz[((size_t)row << 11) + col];
                    const float z_  = (float)rz[((size_t)row << 11) + 1024 + col];
                    const float inv = (float)inb[((size_t)row << 10) + col];
                    const float nn  = fast_tanh(inv + r_ * hn);
                    const float htv = (float)xh_ht[(size_t)row * 1280 + col];  // RK4 ht (bf16)
                    outp[(size_t)row * 1040 + 16 + col] = (1.f - z_) * nn + z_ * htv;
                }
            }
        }
    }
}

// ---------------- readout: out[:, :16] ----------------
__global__ void k_ly(const float* __restrict__ outh, const float* __restrict__ state,
                     const float* __restrict__ Wly, const float* __restrict__ bly,
                     const int* __restrict__ y_type, float* __restrict__ outp, int B) {
    int t = blockIdx.x * 256 + threadIdx.x;
    if (t >= B * 16) return;
    int o = t & 15, b = t >> 4;
    const float4* hrow = (const float4*)(outh + (size_t)b * 1040 + 16);
    float s = bly[o];
#pragma unroll 4
    for (int k4 = 0; k4 < 256; ++k4) {
        float4 h = hrow[k4];
        int k = k4 << 2;
        s += h.x * Wly[(k + 0) * 16 + o] + h.y * Wly[(k + 1) * 16 + o]
           + h.z * Wly[(k + 2) * 16 + o] + h.w * Wly[(k + 3) * 16 + o];
    }
    outp[(size_t)b * 1040 + o] = (y_type[o] == 0) ? s : state[(size_t)b * 1040 + o];
}

// ---------------- launcher ----------------
extern "C" void kernel_launch(void* const* d_in, const int* in_sizes, int n_in,
                              void* d_out, int out_size, void* d_ws, size_t ws_size,
                              hipStream_t stream) {
    const float* state = (const float*)d_in[0];
    const float* xt    = (const float*)d_in[1];
    const float* W1    = (const float*)d_in[2];
    const float* b1    = (const float*)d_in[3];
    const float* W2    = (const float*)d_in[4];
    const float* b2    = (const float*)d_in[5];
    const float* Wih   = (const float*)d_in[6];
    const float* Whh   = (const float*)d_in[7];
    const float* bih   = (const float*)d_in[8];
    const float* bhh   = (const float*)d_in[9];
    const float* Wly   = (const float*)d_in[10];
    const float* bly   = (const float*)d_in[11];
    const int*   y_type = (const int*)d_in[12];
    float* out = (float*)d_out;

    const int B = in_sizes[0] / 1040;   // 32768

    char* ws = (char*)d_ws;
    bf16_t* w1t  = (bf16_t*)(ws);                    // 2048 x 1024
    bf16_t* w2t  = (bf16_t*)(ws + 4194304);          // 1024 x 2048
    bf16_t* wrz  = (bf16_t*)(ws + 8388608);          // 2048 x 1280
    bf16_t* win  = (bf16_t*)(ws + 13631488);         // 1024 x 256
    bf16_t* whn  = (bf16_t*)(ws + 14155776);         // 1024 x 1024
    float*  brz  = (float*) (ws + 16252928);         // 2048
    bf16_t* xh   = (bf16_t*)(ws + 16261120);         // B x 1280 ([x | ht_])
    bf16_t* hs   = (bf16_t*)(ws + 100147200);        // B x 1024 (RK4 stage input)
    bf16_t* h0b  = (bf16_t*)(ws + 167256064);        // B x 1024 (h0 bf16; later i_n)
    bf16_t* inbf = h0b;                              // i_n output reuses h0b space
    bf16_t* T    = (bf16_t*)(ws + 234364928);        // B x 2048 (tanh act; later r/z)
    bf16_t* kacc = (bf16_t*)(ws + 368582656);        // B x 1024 (k-sum, bf16)

    // weight prep + input casts
    k_cvt_transpose<<<(1024 * 2048) / 256, 256, 0, stream>>>(W1, w1t, 1024, 2048);
    k_cvt_transpose<<<(2048 * 1024) / 256, 256, 0, stream>>>(W2, w2t, 2048, 1024);
    k_build_wrz<<<(2048 * 1280) / 256, 256, 0, stream>>>(Wih, Whh, bih, bhh, wrz, brz);
    k_cvt_flat<<<(1024 * 256) / 256, 256, 0, stream>>>(Wih + 2048 * 256, win, 1024 * 256);
    k_cvt_flat<<<(1024 * 1024) / 256, 256, 0, stream>>>(Whh + 2048 * 1024, whn, 1024 * 1024);
    k_cvt_x<<<(B * 256) / 256, 256, 0, stream>>>(xt, xh, B);
    k_cvt_h0<<<(B * 1024) / 256, 256, 0, stream>>>(state, h0b, B);

    const dim3 blk(256);
    const int MB = B / 128;   // 256 m-tiles

    // ---- RK4: 4 stages of (tanh GEMM) -> (W2 GEMM + stage epilogue) ----
    gemm_bt<EPI_TANH, 0><<<dim3(16, MB), blk, 0, stream>>>(h0b, 1024, w1t, 2048, 1024, b1, T,
        nullptr, nullptr, nullptr, nullptr, nullptr, nullptr, nullptr);
    gemm_bt<EPI_RK4, 0><<<dim3(8, MB), blk, 0, stream>>>(T, 2048, w2t, 1024, 2048, b2, hs,
        h0b, state, kacc, out, xh + 256, nullptr, nullptr);

    gemm_bt<EPI_TANH, 0><<<dim3(16, MB), blk, 0, stream>>>(hs, 1024, w1t, 2048, 1024, b1, T,
        nullptr, nullptr, nullptr, nullptr, nullptr, nullptr, nullptr);
    gemm_bt<EPI_RK4, 1><<<dim3(8, MB), blk, 0, stream>>>(T, 2048, w2t, 1024, 2048, b2, hs,
        h0b, state, kacc, out, xh + 256, nullptr, nullptr);

    gemm_bt<EPI_TANH, 0><<<dim3(16, MB), blk, 0, stream>>>(hs, 1024, w1t, 2048, 1024, b1, T,
        nullptr, nullptr, nullptr, nullptr, nullptr, nullptr, nullptr);
    gemm_bt<EPI_RK4, 2><<<dim3(8, MB), blk, 0, stream>>>(T, 2048, w2t, 1024, 2048, b2, hs,
        h0b, state, kacc, out, xh + 256, nullptr, nullptr);

    gemm_bt<EPI_TANH, 0><<<dim3(16, MB), blk, 0, stream>>>(hs, 1024, w1t, 2048, 1024, b1, T,
        nullptr, nullptr, nullptr, nullptr, nullptr, nullptr, nullptr);
    gemm_bt<EPI_RK4, 3><<<dim3(8, MB), blk, 0, stream>>>(T, 2048, w2t, 1024, 2048, b2, hs,
        h0b, state, kacc, out, xh + 256, nullptr, nullptr);

    // ---- GRU ----
    // r,z gates: [x|ht_] (K=1280) @ wrz^T -> sigmoid -> T (B x 2048 bf16)
    gemm_bt<EPI_SIG, 0><<<dim3(16, MB), blk, 0, stream>>>(xh, 1280, wrz, 2048, 1280, brz, T,
        nullptr, nullptr, nullptr, nullptr, nullptr, nullptr, nullptr);
    // i_n: x (K=256) @ Wih_n^T + bih_n -> bf16 (into h0b space, h0b dead now)
    gemm_bt<EPI_BIASBF, 0><<<dim3(8, MB), blk, 0, stream>>>(xh, 1280, win, 1024, 256,
        bih + 2048, inbf, nullptr, nullptr, nullptr, nullptr, nullptr, nullptr, nullptr);
    // h_n GEMM + full GRU merge -> out[:, 16:]
    gemm_bt<EPI_FIN, 0><<<dim3(8, MB), blk, 0, stream>>>(xh + 256, 1280, whn, 1024, 1024,
        bhh + 2048, nullptr, nullptr, nullptr, nullptr, out, xh + 256, T, inbf);

    // ---- readout out[:, :16] ----
    k_ly<<<(B * 16) / 256, 256, 0, stream>>>(out, state, Wly, bly, y_type, out, B);
}

// Round 3
// 2717.083 us; speedup vs baseline: 1.1650x; 1.0548x over previous
//
#include <hip/hip_runtime.h>
#include <cstdint>
#include <cstddef>

typedef __bf16 bf16_t;
typedef __attribute__((ext_vector_type(8))) __bf16 bf16x8;
typedef __attribute__((ext_vector_type(4))) float f32x4;

__device__ __forceinline__ void async_cp16(const void* g, void* l) {
    __builtin_amdgcn_global_load_lds(
        (const __attribute__((address_space(1))) void*)g,
        (__attribute__((address_space(3))) void*)l,
        16, 0, 0);
}

__device__ __forceinline__ float fast_tanh(float x) {
    float ax = fabsf(x);
    float e = __expf(-2.f * ax);
    float t = (1.f - e) / (1.f + e);
    return x < 0.f ? -t : t;
}
__device__ __forceinline__ float fast_sig(float x) {
    return 1.f / (1.f + __expf(-x));
}

// ---------------- conversion kernels ----------------
__global__ void k_cvt_transpose(const float* __restrict__ src, bf16_t* __restrict__ dst,
                                int K, int N) {
    int idx = blockIdx.x * 256 + threadIdx.x;
    if (idx >= K * N) return;
    int k = idx / N, n = idx - k * N;
    dst[(size_t)n * K + k] = (bf16_t)src[idx];
}

__global__ void k_cvt_flat(const float* __restrict__ src, bf16_t* __restrict__ dst, int n) {
    int idx = blockIdx.x * 256 + threadIdx.x;
    if (idx >= n) return;
    dst[idx] = (bf16_t)src[idx];
}

__global__ void k_build_wrz(const float* __restrict__ Wih, const float* __restrict__ Whh,
                            const float* __restrict__ bih, const float* __restrict__ bhh,
                            bf16_t* __restrict__ wrz, float* __restrict__ brz) {
    int idx = blockIdx.x * 256 + threadIdx.x;
    if (idx >= 2048 * 1280) return;
    int n = idx / 1280, c = idx - n * 1280;
    float v = (c < 256) ? Wih[(size_t)n * 256 + c] : Whh[(size_t)n * 1024 + (c - 256)];
    wrz[idx] = (bf16_t)v;
    if (c == 0) brz[n] = bih[n] + bhh[n];
}

__global__ void k_cvt_x(const float* __restrict__ xt, bf16_t* __restrict__ xh, int B) {
    int idx = blockIdx.x * 256 + threadIdx.x;
    if (idx >= B * 256) return;
    int b = idx >> 8, c = idx & 255;
    xh[(size_t)b * 1280 + c] = (bf16_t)xt[idx];
}

__global__ void k_cvt_h0(const float* __restrict__ state, bf16_t* __restrict__ h0b, int B) {
    int idx = blockIdx.x * 256 + threadIdx.x;
    if (idx >= B * 1024) return;
    int b = idx >> 10, j = idx & 1023;
    h0b[idx] = (bf16_t)state[(size_t)b * 1040 + 16 + j];
}

// ---------------- GEMM: C(MxN) = A(MxK) * Bt(NxK)^T, bf16 in, f32 acc ----------------
// 256x256 tile, BK=32, 512 threads (8 waves, 2M x 4N; wave = 128x64 output).
// 4-slot LDS pipeline (128 KiB), prefetch depth 2, counted vmcnt(4) + raw s_barrier.
// XOR bank swizzle: lds[row][s] holds global col-slot s ^ ((row>>1)&3)  (involution,
// applied to BOTH the global staging source and the ds_read address -> consistent).
enum { EPI_TANH = 0, EPI_RK4 = 1, EPI_SIG = 2, EPI_BIASBF = 3, EPI_FIN = 4 };

template <int EPI, int STAGE>
__global__ __launch_bounds__(512, 2) void gemm256(
    const bf16_t* __restrict__ A, int lda,
    const bf16_t* __restrict__ Bt,
    int N, int K,
    const float* __restrict__ bias,
    bf16_t* __restrict__ obf,
    const bf16_t* __restrict__ h0b,   // B x 1024 bf16 (RK4 stages 0-2)
    const float* __restrict__ state,  // f32, ld 1040 (RK4 stage 3 only)
    bf16_t* __restrict__ kacc,        // B x 1024 bf16 (k-sum)
    float* __restrict__ outp,         // f32 out, ld 1040
    bf16_t* __restrict__ xh_ht,       // = xh + 256 (ld 1280): stage-3 write / FIN ht read
    const bf16_t* __restrict__ rz,    // B x 2048 bf16 (FIN)
    const bf16_t* __restrict__ inb)   // B x 1024 bf16 (FIN)
{
    __shared__ __align__(16) bf16_t As[4][8192];   // 4 slots x 256 rows x 32 k
    __shared__ __align__(16) bf16_t Bs[4][8192];

    const int tid  = threadIdx.x;
    const int lane = tid & 63;
    const int wv   = tid >> 6;

    // XCD-aware bijective swizzle (all grids here have nwg % 8 == 0)
    const int gx  = gridDim.x;
    int bid = blockIdx.y * gx + blockIdx.x;
    const int nwg = gx * gridDim.y;
    if ((nwg & 7) == 0) {
        bid = (bid & 7) * (nwg >> 3) + (bid >> 3);
    }
    const int bm = (bid / gx) << 8;
    const int bn = (bid % gx) << 8;

    const int wm = (wv >> 2) << 7;   // 0 or 128
    const int wn = (wv & 3) << 6;    // 0,64,128,192

    f32x4 acc[8][4] = {};

    // ---- staging addresses (linear LDS dest, swizzled global source) ----
    const int srow = tid >> 2;                 // 0..127 (local row, issue0)
    const int s4   = tid & 3;                  // 16B slot within 64B row
    const int scw  = (s4 ^ ((srow >> 1) & 3)) << 3;   // swizzled col (elems)
    const bf16_t* gA0 = A  + (size_t)(bm + srow) * lda + scw;
    const bf16_t* gA1 = gA0 + (size_t)128 * lda;
    const bf16_t* gB0 = Bt + (size_t)(bn + srow) * K + scw;
    const bf16_t* gB1 = gB0 + (size_t)128 * K;
    const int ldsOff = tid << 3;               // elem offset, 16B per thread

#define STAGE_KT(kk) do {                                              \
        const int _sl = (kk) & 3; const size_t _ko = (size_t)(kk) << 5; \
        async_cp16(gA0 + _ko, (void*)&As[_sl][ldsOff]);                 \
        async_cp16(gA1 + _ko, (void*)&As[_sl][4096 + ldsOff]);          \
        async_cp16(gB0 + _ko, (void*)&Bs[_sl][ldsOff]);                 \
        async_cp16(gB1 + _ko, (void*)&Bs[_sl][4096 + ldsOff]);          \
    } while (0)

    // ---- fragment LDS offsets (within a slot), swizzled read ----
    const int fr = lane & 15;
    const int kg = lane >> 4;
    int aoff[8], boff[4];
#pragma unroll
    for (int i = 0; i < 8; ++i) {
        const int r = wm + i * 16 + fr;
        aoff[i] = r * 32 + ((kg ^ ((r >> 1) & 3)) << 3);
    }
#pragma unroll
    for (int j = 0; j < 4; ++j) {
        const int r = wn + j * 16 + fr;
        boff[j] = r * 32 + ((kg ^ ((r >> 1) & 3)) << 3);
    }

    const int NT = K >> 5;

    // prologue: stage K-tiles 0 and 1 (8 loads/thread outstanding)
    STAGE_KT(0);
    STAGE_KT(1);

    for (int kt = 0; kt < NT; ++kt) {
        // gate: slot kt&3 complete.  Steady state: outstanding = kt's 4 + (kt+1)'s 4.
        if (kt + 1 < NT) {
            asm volatile("s_waitcnt vmcnt(4)" ::: "memory");
        } else {
            asm volatile("s_waitcnt vmcnt(0)" ::: "memory");
        }
        __builtin_amdgcn_s_barrier();   // raw: no vmcnt(0) drain of fresh prefetches

        if (kt + 2 < NT) STAGE_KT(kt + 2);

        const bf16_t* as = As[kt & 3];
        const bf16_t* bs = Bs[kt & 3];
        bf16x8 af[8], bfr[4];
#pragma unroll
        for (int i = 0; i < 8; ++i) af[i]  = *(const bf16x8*)(as + aoff[i]);
#pragma unroll
        for (int j = 0; j < 4; ++j) bfr[j] = *(const bf16x8*)(bs + boff[j]);

        __builtin_amdgcn_s_setprio(1);
#pragma unroll
        for (int i = 0; i < 8; ++i)
#pragma unroll
            for (int j = 0; j < 4; ++j)
                acc[i][j] = __builtin_amdgcn_mfma_f32_16x16x32_bf16(af[i], bfr[j], acc[i][j], 0, 0, 0);
        __builtin_amdgcn_s_setprio(0);
    }
#undef STAGE_KT

    // C/D layout (verified m89/m91): col = lane&15, row = (lane>>4)*4 + reg
    const int orow0 = bm + wm + (kg << 2);
    const int ocol0 = bn + wn + fr;
#pragma unroll
    for (int i = 0; i < 8; ++i) {
#pragma unroll
        for (int j = 0; j < 4; ++j) {
#pragma unroll
            for (int r = 0; r < 4; ++r) {
                const int row = orow0 + i * 16 + r;
                const int col = ocol0 + j * 16;
                const float c = acc[i][j][r];
                if constexpr (EPI == EPI_TANH) {
                    obf[(size_t)row * N + col] = (bf16_t)fast_tanh(c + bias[col]);
                } else if constexpr (EPI == EPI_RK4) {
                    const float kk = c + bias[col];
                    const size_t hidx = ((size_t)row << 10) + col;
                    if constexpr (STAGE == 0) {
                        const float h0 = (float)h0b[hidx];
                        kacc[hidx] = (bf16_t)kk;
                        obf[hidx] = (bf16_t)(h0 + 0.05f * kk);
                    } else if constexpr (STAGE == 1) {
                        const float h0 = (float)h0b[hidx];
                        kacc[hidx] = (bf16_t)((float)kacc[hidx] + 2.f * kk);
                        obf[hidx] = (bf16_t)(h0 + 0.05f * kk);
                    } else if constexpr (STAGE == 2) {
                        const float h0 = (float)h0b[hidx];
                        kacc[hidx] = (bf16_t)((float)kacc[hidx] + 2.f * kk);
                        obf[hidx] = (bf16_t)(h0 + 0.1f * kk);
                    } else {
                        const float h0 = state[(size_t)row * 1040 + 16 + col];
                        const float ht = h0 + (0.1f / 6.f) * ((float)kacc[hidx] + kk);
                        outp[(size_t)row * 1040 + 16 + col] = ht;
                        xh_ht[(size_t)row * 1280 + col] = (bf16_t)ht;
                    }
                } else if constexpr (EPI == EPI_SIG) {
                    obf[(size_t)row * N + col] = (bf16_t)fast_sig(c + bias[col]);
                } else if constexpr (EPI == EPI_BIASBF) {
                    obf[(size_t)row * N + col] = (bf16_t)(c + bias[col]);
                } else {  // EPI_FIN
                    const float hn  = c + bias[col];
                    const float r_  = (float)rz[((size_t)row << 11) + col];
                    const float z_  = (float)rz[((size_t)row << 11) + 1024 + col];
                    const float inv = (float)inb[((size_t)row << 10) + col];
                    const float nn  = fast_tanh(inv + r_ * hn);
                    const float htv = (float)xh_ht[(size_t)row * 1280 + col];
                    outp[(size_t)row * 1040 + 16 + col] = (1.f - z_) * nn + z_ * htv;
                }
            }
        }
    }
}

// ---------------- readout: out[:, :16] ----------------
__global__ void k_ly(const float* __restrict__ outh, const float* __restrict__ state,
                     const float* __restrict__ Wly, const float* __restrict__ bly,
                     const int* __restrict__ y_type, float* __restrict__ outp, int B) {
    int t = blockIdx.x * 256 + threadIdx.x;
    if (t >= B * 16) return;
    int o = t & 15, b = t >> 4;
    const float4* hrow = (const float4*)(outh + (size_t)b * 1040 + 16);
    float s = bly[o];
#pragma unroll 4
    for (int k4 = 0; k4 < 256; ++k4) {
        float4 h = hrow[k4];
        int k = k4 << 2;
        s += h.x * Wly[(k + 0) * 16 + o] + h.y * Wly[(k + 1) * 16 + o]
           + h.z * Wly[(k + 2) * 16 + o] + h.w * Wly[(k + 3) * 16 + o];
    }
    outp[(size_t)b * 1040 + o] = (y_type[o] == 0) ? s : state[(size_t)b * 1040 + o];
}

// ---------------- launcher ----------------
extern "C" void kernel_launch(void* const* d_in, const int* in_sizes, int n_in,
                              void* d_out, int out_size, void* d_ws, size_t ws_size,
                              hipStream_t stream) {
    const float* state = (const float*)d_in[0];
    const float* xt    = (const float*)d_in[1];
    const float* W1    = (const float*)d_in[2];
    const float* b1    = (const float*)d_in[3];
    const float* W2    = (const float*)d_in[4];
    const float* b2    = (const float*)d_in[5];
    const float* Wih   = (const float*)d_in[6];
    const float* Whh   = (const float*)d_in[7];
    const float* bih   = (const float*)d_in[8];
    const float* bhh   = (const float*)d_in[9];
    const float* Wly   = (const float*)d_in[10];
    const float* bly   = (const float*)d_in[11];
    const int*   y_type = (const int*)d_in[12];
    float* out = (float*)d_out;

    const int B = in_sizes[0] / 1040;   // 32768

    char* ws = (char*)d_ws;
    bf16_t* w1t  = (bf16_t*)(ws);                    // 2048 x 1024
    bf16_t* w2t  = (bf16_t*)(ws + 4194304);          // 1024 x 2048
    bf16_t* wrz  = (bf16_t*)(ws + 8388608);          // 2048 x 1280
    bf16_t* win  = (bf16_t*)(ws + 13631488);         // 1024 x 256
    bf16_t* whn  = (bf16_t*)(ws + 14155776);         // 1024 x 1024
    float*  brz  = (float*) (ws + 16252928);         // 2048
    bf16_t* xh   = (bf16_t*)(ws + 16261120);         // B x 1280 ([x | ht_])
    bf16_t* hs   = (bf16_t*)(ws + 100147200);        // B x 1024 (RK4 stage input)
    bf16_t* h0b  = (bf16_t*)(ws + 167256064);        // B x 1024 (h0 bf16; later i_n)
    bf16_t* inbf = h0b;                              // i_n output reuses h0b space
    bf16_t* T    = (bf16_t*)(ws + 234364928);        // B x 2048 (tanh act; later r/z)
    bf16_t* kacc = (bf16_t*)(ws + 368582656);        // B x 1024 (k-sum, bf16)

    // weight prep + input casts
    k_cvt_transpose<<<(1024 * 2048) / 256, 256, 0, stream>>>(W1, w1t, 1024, 2048);
    k_cvt_transpose<<<(2048 * 1024) / 256, 256, 0, stream>>>(W2, w2t, 2048, 1024);
    k_build_wrz<<<(2048 * 1280) / 256, 256, 0, stream>>>(Wih, Whh, bih, bhh, wrz, brz);
    k_cvt_flat<<<(1024 * 256) / 256, 256, 0, stream>>>(Wih + 2048 * 256, win, 1024 * 256);
    k_cvt_flat<<<(1024 * 1024) / 256, 256, 0, stream>>>(Whh + 2048 * 1024, whn, 1024 * 1024);
    k_cvt_x<<<(B * 256) / 256, 256, 0, stream>>>(xt, xh, B);
    k_cvt_h0<<<(B * 1024) / 256, 256, 0, stream>>>(state, h0b, B);

    const dim3 blk(512);
    const int MB = B / 256;   // 128 m-tiles

    // ---- RK4: 4 stages of (tanh GEMM) -> (W2 GEMM + stage epilogue) ----
    gemm256<EPI_TANH, 0><<<dim3(8, MB), blk, 0, stream>>>(h0b, 1024, w1t, 2048, 1024, b1, T,
        nullptr, nullptr, nullptr, nullptr, nullptr, nullptr, nullptr);
    gemm256<EPI_RK4, 0><<<dim3(4, MB), blk, 0, stream>>>(T, 2048, w2t, 1024, 2048, b2, hs,
        h0b, state, kacc, out, xh + 256, nullptr, nullptr);

    gemm256<EPI_TANH, 0><<<dim3(8, MB), blk, 0, stream>>>(hs, 1024, w1t, 2048, 1024, b1, T,
        nullptr, nullptr, nullptr, nullptr, nullptr, nullptr, nullptr);
    gemm256<EPI_RK4, 1><<<dim3(4, MB), blk, 0, stream>>>(T, 2048, w2t, 1024, 2048, b2, hs,
        h0b, state, kacc, out, xh + 256, nullptr, nullptr);

    gemm256<EPI_TANH, 0><<<dim3(8, MB), blk, 0, stream>>>(hs, 1024, w1t, 2048, 1024, b1, T,
        nullptr, nullptr, nullptr, nullptr, nullptr, nullptr, nullptr);
    gemm256<EPI_RK4, 2><<<dim3(4, MB), blk, 0, stream>>>(T, 2048, w2t, 1024, 2048, b2, hs,
        h0b, state, kacc, out, xh + 256, nullptr, nullptr);

    gemm256<EPI_TANH, 0><<<dim3(8, MB), blk, 0, stream>>>(hs, 1024, w1t, 2048, 1024, b1, T,
        nullptr, nullptr, nullptr, nullptr, nullptr, nullptr, nullptr);
    gemm256<EPI_RK4, 3><<<dim3(4, MB), blk, 0, stream>>>(T, 2048, w2t, 1024, 2048, b2, hs,
        h0b, state, kacc, out, xh + 256, nullptr, nullptr);

    // ---- GRU ----
    // r,z gates: [x|ht_] (K=1280) @ wrz^T -> sigmoid -> T (B x 2048 bf16)
    gemm256<EPI_SIG, 0><<<dim3(8, MB), blk, 0, stream>>>(xh, 1280, wrz, 2048, 1280, brz, T,
        nullptr, nullptr, nullptr, nullptr, nullptr, nullptr, nullptr);
    // i_n: x (K=256) @ Wih_n^T + bih_n -> bf16 (into h0b space, h0b dead now)
    gemm256<EPI_BIASBF, 0><<<dim3(4, MB), blk, 0, stream>>>(xh, 1280, win, 1024, 256,
        bih + 2048, inbf, nullptr, nullptr, nullptr, nullptr, nullptr, nullptr, nullptr);
    // h_n GEMM + full GRU merge -> out[:, 16:]
    gemm256<EPI_FIN, 0><<<dim3(4, MB), blk, 0, stream>>>(xh + 256, 1280, whn, 1024, 1024,
        bhh + 2048, nullptr, nullptr, nullptr, nullptr, out, xh + 256, T, inbf);

    // ---- readout out[:, :16] ----
    k_ly<<<(B * 16) / 256, 256, 0, stream>>>(out, state, Wly, bly, y_type, out, B);
}

// Round 4
// 2309.735 us; speedup vs baseline: 1.3704x; 1.1764x over previous
//
#include <hip/hip_runtime.h>
#include <cstdint>
#include <cstddef>

typedef __bf16 bf16_t;
typedef __attribute__((ext_vector_type(8))) __bf16 bf16x8;
typedef __attribute__((ext_vector_type(4))) float f32x4;

__device__ __forceinline__ void async_cp16(const void* g, void* l) {
    __builtin_amdgcn_global_load_lds(
        (const __attribute__((address_space(1))) void*)g,
        (__attribute__((address_space(3))) void*)l,
        16, 0, 0);
}

__device__ __forceinline__ float fast_tanh(float x) {
    float ax = fabsf(x);
    float e = __expf(-2.f * ax);
    float t = (1.f - e) / (1.f + e);
    return x < 0.f ? -t : t;
}
__device__ __forceinline__ float fast_sig(float x) {
    return 1.f / (1.f + __expf(-x));
}

// ---------------- conversion kernels ----------------
__global__ void k_cvt_transpose(const float* __restrict__ src, bf16_t* __restrict__ dst,
                                int K, int N) {
    int idx = blockIdx.x * 256 + threadIdx.x;
    if (idx >= K * N) return;
    int k = idx / N, n = idx - k * N;
    dst[(size_t)n * K + k] = (bf16_t)src[idx];
}

__global__ void k_cvt_flat(const float* __restrict__ src, bf16_t* __restrict__ dst, int n) {
    int idx = blockIdx.x * 256 + threadIdx.x;
    if (idx >= n) return;
    dst[idx] = (bf16_t)src[idx];
}

__global__ void k_build_wrz(const float* __restrict__ Wih, const float* __restrict__ Whh,
                            const float* __restrict__ bih, const float* __restrict__ bhh,
                            bf16_t* __restrict__ wrz, float* __restrict__ brz) {
    int idx = blockIdx.x * 256 + threadIdx.x;
    if (idx >= 2048 * 1280) return;
    int n = idx / 1280, c = idx - n * 1280;
    float v = (c < 256) ? Wih[(size_t)n * 256 + c] : Whh[(size_t)n * 1024 + (c - 256)];
    wrz[idx] = (bf16_t)v;
    if (c == 0) brz[n] = bih[n] + bhh[n];
}

__global__ void k_cvt_x(const float* __restrict__ xt, bf16_t* __restrict__ xh, int B) {
    int idx = blockIdx.x * 256 + threadIdx.x;
    if (idx >= B * 256) return;
    int b = idx >> 8, c = idx & 255;
    xh[(size_t)b * 1280 + c] = (bf16_t)xt[idx];
}

__global__ void k_cvt_h0(const float* __restrict__ state, bf16_t* __restrict__ h0b, int B) {
    int idx = blockIdx.x * 256 + threadIdx.x;
    if (idx >= B * 1024) return;
    int b = idx >> 10, j = idx & 1023;
    h0b[idx] = (bf16_t)state[(size_t)b * 1040 + 16 + j];
}

// ---------------- GEMM: C(MxN) = A(MxK) * Bt(NxK)^T, bf16 in, f32 acc ----------------
// 128x256 tile, BK=32, 512 threads (8 waves, 2M x 4N; wave = 64x64 output).
// 3-slot LDS pipeline (72 KiB -> 2 blocks/CU for TLP stall-filling), prefetch depth 2,
// counted vmcnt(3) + raw s_barrier.  XOR bank swizzle (involution, applied to BOTH the
// global staging source and the ds_read address): lds[row][s] holds global slot
// s ^ ((row>>1)&3).  Verified 0 bank conflicts in round 3.
enum { EPI_TANH = 0, EPI_RK4 = 1, EPI_SIG = 2, EPI_BIASBF = 3, EPI_FIN = 4 };

template <int EPI, int STAGE>
__global__ __launch_bounds__(512, 4) void gemm128(
    const bf16_t* __restrict__ A, int lda,
    const bf16_t* __restrict__ Bt,
    int N, int K,
    const float* __restrict__ bias,
    bf16_t* __restrict__ obf,
    const bf16_t* __restrict__ h0b,   // B x 1024 bf16 (RK4 stages 0-2)
    const float* __restrict__ state,  // f32, ld 1040 (RK4 stage 3 only)
    bf16_t* __restrict__ kacc,        // B x 1024 bf16 (k-sum)
    float* __restrict__ outp,         // f32 out, ld 1040
    bf16_t* __restrict__ xh_ht,       // = xh + 256 (ld 1280): stage-3 write / FIN ht read
    const bf16_t* __restrict__ rz,    // B x 2048 bf16 (FIN)
    const bf16_t* __restrict__ inb)   // B x 1024 bf16 (FIN)
{
    __shared__ __align__(16) bf16_t As[3][4096];   // 3 slots x 128 rows x 32 k
    __shared__ __align__(16) bf16_t Bs[3][8192];   // 3 slots x 256 rows x 32 k

    const int tid  = threadIdx.x;
    const int lane = tid & 63;
    const int wv   = tid >> 6;

    // XCD-aware bijective swizzle (all grids here have nwg % 8 == 0)
    const int gx  = gridDim.x;
    int bid = blockIdx.y * gx + blockIdx.x;
    const int nwg = gx * gridDim.y;
    if ((nwg & 7) == 0) {
        bid = (bid & 7) * (nwg >> 3) + (bid >> 3);
    }
    const int bm = (bid / gx) << 7;   // 128-row tiles
    const int bn = (bid % gx) << 8;   // 256-col tiles

    const int wm = (wv >> 2) << 6;    // 0 or 64
    const int wn = (wv & 3) << 6;     // 0,64,128,192

    f32x4 acc[4][4] = {};

    // ---- staging (linear LDS dest, swizzled global source) ----
    const int srow = tid >> 2;                        // 0..127
    const int s4   = tid & 3;
    const int scw  = (s4 ^ ((srow >> 1) & 3)) << 3;   // swizzled col (elems)
    const bf16_t* gA0 = A  + (size_t)(bm + srow) * lda + scw;
    const bf16_t* gB0 = Bt + (size_t)(bn + srow) * K + scw;
    const bf16_t* gB1 = gB0 + (size_t)128 * K;        // rows+128: same swizzle term
    const int ldsOff = tid << 3;                      // 16B per thread

    // 3 load-instructions per wave per K-tile  ->  gate = vmcnt(3)
#define STAGE_KT(kk) do {                                               \
        const int _sl = (kk) % 3; const size_t _ko = (size_t)(kk) << 5; \
        async_cp16(gA0 + _ko, (void*)&As[_sl][ldsOff]);                 \
        async_cp16(gB0 + _ko, (void*)&Bs[_sl][ldsOff]);                 \
        async_cp16(gB1 + _ko, (void*)&Bs[_sl][4096 + ldsOff]);          \
    } while (0)

    // ---- fragment LDS offsets (within a slot), swizzled read ----
    // swizzle term ((r>>1)&3) is invariant in i/j steps of 16 rows
    const int fr = lane & 15;
    const int kg = lane >> 4;
    const int ra = wm + fr;
    const int rb = wn + fr;
    const int aoff0 = ra * 32 + ((kg ^ ((ra >> 1) & 3)) << 3);
    const int boff0 = rb * 32 + ((kg ^ ((rb >> 1) & 3)) << 3);

    const int NT = K >> 5;

    STAGE_KT(0);
    STAGE_KT(1);

    for (int kt = 0; kt < NT; ++kt) {
        if (kt + 1 < NT) {
            asm volatile("s_waitcnt vmcnt(3)" ::: "memory");   // slot kt complete
        } else {
            asm volatile("s_waitcnt vmcnt(0)" ::: "memory");
        }
        __builtin_amdgcn_s_barrier();   // raw: no drain of in-flight prefetches

        if (kt + 2 < NT) STAGE_KT(kt + 2);

        const int sl = kt % 3;
        const bf16_t* as = &As[sl][0];
        const bf16_t* bs = &Bs[sl][0];
        bf16x8 af[4], bfr[4];
#pragma unroll
        for (int i = 0; i < 4; ++i) af[i]  = *(const bf16x8*)(as + aoff0 + i * 512);
#pragma unroll
        for (int j = 0; j < 4; ++j) bfr[j] = *(const bf16x8*)(bs + boff0 + j * 512);

        __builtin_amdgcn_s_setprio(1);
#pragma unroll
        for (int i = 0; i < 4; ++i)
#pragma unroll
            for (int j = 0; j < 4; ++j)
                acc[i][j] = __builtin_amdgcn_mfma_f32_16x16x32_bf16(af[i], bfr[j], acc[i][j], 0, 0, 0);
        __builtin_amdgcn_s_setprio(0);
    }
#undef STAGE_KT

    // C/D layout (verified m89/m91): col = lane&15, row = (lane>>4)*4 + reg
    const int orow0 = bm + wm + (kg << 2);
    const int ocol0 = bn + wn + fr;
#pragma unroll
    for (int i = 0; i < 4; ++i) {
#pragma unroll
        for (int j = 0; j < 4; ++j) {
#pragma unroll
            for (int r = 0; r < 4; ++r) {
                const int row = orow0 + i * 16 + r;
                const int col = ocol0 + j * 16;
                const float c = acc[i][j][r];
                if constexpr (EPI == EPI_TANH) {
                    obf[(size_t)row * N + col] = (bf16_t)fast_tanh(c + bias[col]);
                } else if constexpr (EPI == EPI_RK4) {
                    const float kk = c + bias[col];
                    const size_t hidx = ((size_t)row << 10) + col;
                    if constexpr (STAGE == 0) {
                        const float h0 = (float)h0b[hidx];
                        kacc[hidx] = (bf16_t)kk;
                        obf[hidx] = (bf16_t)(h0 + 0.05f * kk);
                    } else if constexpr (STAGE == 1) {
                        const float h0 = (float)h0b[hidx];
                        kacc[hidx] = (bf16_t)((float)kacc[hidx] + 2.f * kk);
                        obf[hidx] = (bf16_t)(h0 + 0.05f * kk);
                    } else if constexpr (STAGE == 2) {
                        const float h0 = (float)h0b[hidx];
                        kacc[hidx] = (bf16_t)((float)kacc[hidx] + 2.f * kk);
                        obf[hidx] = (bf16_t)(h0 + 0.1f * kk);
                    } else {
                        const float h0 = state[(size_t)row * 1040 + 16 + col];
                        const float ht = h0 + (0.1f / 6.f) * ((float)kacc[hidx] + kk);
                        outp[(size_t)row * 1040 + 16 + col] = ht;
                        xh_ht[(size_t)row * 1280 + col] = (bf16_t)ht;
                    }
                } else if constexpr (EPI == EPI_SIG) {
                    obf[(size_t)row * N + col] = (bf16_t)fast_sig(c + bias[col]);
                } else if constexpr (EPI == EPI_BIASBF) {
                    obf[(size_t)row * N + col] = (bf16_t)(c + bias[col]);
                } else {  // EPI_FIN
                    const float hn  = c + bias[col];
                    const float r_  = (float)rz[((size_t)row << 11) + col];
                    const float z_  = (float)rz[((size_t)row << 11) + 1024 + col];
                    const float inv = (float)inb[((size_t)row << 10) + col];
                    const float nn  = fast_tanh(inv + r_ * hn);
                    const float htv = (float)xh_ht[(size_t)row * 1280 + col];
                    outp[(size_t)row * 1040 + 16 + col] = (1.f - z_) * nn + z_ * htv;
                }
            }
        }
    }
}

// ---------------- readout: out[:, :16] ----------------
__global__ void k_ly(const float* __restrict__ outh, const float* __restrict__ state,
                     const float* __restrict__ Wly, const float* __restrict__ bly,
                     const int* __restrict__ y_type, float* __restrict__ outp, int B) {
    int t = blockIdx.x * 256 + threadIdx.x;
    if (t >= B * 16) return;
    int o = t & 15, b = t >> 4;
    const float4* hrow = (const float4*)(outh + (size_t)b * 1040 + 16);
    float s = bly[o];
#pragma unroll 4
    for (int k4 = 0; k4 < 256; ++k4) {
        float4 h = hrow[k4];
        int k = k4 << 2;
        s += h.x * Wly[(k + 0) * 16 + o] + h.y * Wly[(k + 1) * 16 + o]
           + h.z * Wly[(k + 2) * 16 + o] + h.w * Wly[(k + 3) * 16 + o];
    }
    outp[(size_t)b * 1040 + o] = (y_type[o] == 0) ? s : state[(size_t)b * 1040 + o];
}

// ---------------- launcher ----------------
extern "C" void kernel_launch(void* const* d_in, const int* in_sizes, int n_in,
                              void* d_out, int out_size, void* d_ws, size_t ws_size,
                              hipStream_t stream) {
    const float* state = (const float*)d_in[0];
    const float* xt    = (const float*)d_in[1];
    const float* W1    = (const float*)d_in[2];
    const float* b1    = (const float*)d_in[3];
    const float* W2    = (const float*)d_in[4];
    const float* b2    = (const float*)d_in[5];
    const float* Wih   = (const float*)d_in[6];
    const float* Whh   = (const float*)d_in[7];
    const float* bih   = (const float*)d_in[8];
    const float* bhh   = (const float*)d_in[9];
    const float* Wly   = (const float*)d_in[10];
    const float* bly   = (const float*)d_in[11];
    const int*   y_type = (const int*)d_in[12];
    float* out = (float*)d_out;

    const int B = in_sizes[0] / 1040;   // 32768

    char* ws = (char*)d_ws;
    bf16_t* w1t  = (bf16_t*)(ws);                    // 2048 x 1024
    bf16_t* w2t  = (bf16_t*)(ws + 4194304);          // 1024 x 2048
    bf16_t* wrz  = (bf16_t*)(ws + 8388608);          // 2048 x 1280
    bf16_t* win  = (bf16_t*)(ws + 13631488);         // 1024 x 256
    bf16_t* whn  = (bf16_t*)(ws + 14155776);         // 1024 x 1024
    float*  brz  = (float*) (ws + 16252928);         // 2048
    bf16_t* xh   = (bf16_t*)(ws + 16261120);         // B x 1280 ([x | ht_])
    bf16_t* hs   = (bf16_t*)(ws + 100147200);        // B x 1024 (RK4 stage input)
    bf16_t* h0b  = (bf16_t*)(ws + 167256064);        // B x 1024 (h0 bf16; later i_n)
    bf16_t* inbf = h0b;                              // i_n output reuses h0b space
    bf16_t* T    = (bf16_t*)(ws + 234364928);        // B x 2048 (tanh act; later r/z)
    bf16_t* kacc = (bf16_t*)(ws + 368582656);        // B x 1024 (k-sum, bf16)

    // weight prep + input casts
    k_cvt_transpose<<<(1024 * 2048) / 256, 256, 0, stream>>>(W1, w1t, 1024, 2048);
    k_cvt_transpose<<<(2048 * 1024) / 256, 256, 0, stream>>>(W2, w2t, 2048, 1024);
    k_build_wrz<<<(2048 * 1280) / 256, 256, 0, stream>>>(Wih, Whh, bih, bhh, wrz, brz);
    k_cvt_flat<<<(1024 * 256) / 256, 256, 0, stream>>>(Wih + 2048 * 256, win, 1024 * 256);
    k_cvt_flat<<<(1024 * 1024) / 256, 256, 0, stream>>>(Whh + 2048 * 1024, whn, 1024 * 1024);
    k_cvt_x<<<(B * 256) / 256, 256, 0, stream>>>(xt, xh, B);
    k_cvt_h0<<<(B * 1024) / 256, 256, 0, stream>>>(state, h0b, B);

    const dim3 blk(512);
    const int MB = B / 128;   // 256 m-tiles

    // ---- RK4: 4 stages of (tanh GEMM) -> (W2 GEMM + stage epilogue) ----
    gemm128<EPI_TANH, 0><<<dim3(8, MB), blk, 0, stream>>>(h0b, 1024, w1t, 2048, 1024, b1, T,
        nullptr, nullptr, nullptr, nullptr, nullptr, nullptr, nullptr);
    gemm128<EPI_RK4, 0><<<dim3(4, MB), blk, 0, stream>>>(T, 2048, w2t, 1024, 2048, b2, hs,
        h0b, state, kacc, out, xh + 256, nullptr, nullptr);

    gemm128<EPI_TANH, 0><<<dim3(8, MB), blk, 0, stream>>>(hs, 1024, w1t, 2048, 1024, b1, T,
        nullptr, nullptr, nullptr, nullptr, nullptr, nullptr, nullptr);
    gemm128<EPI_RK4, 1><<<dim3(4, MB), blk, 0, stream>>>(T, 2048, w2t, 1024, 2048, b2, hs,
        h0b, state, kacc, out, xh + 256, nullptr, nullptr);

    gemm128<EPI_TANH, 0><<<dim3(8, MB), blk, 0, stream>>>(hs, 1024, w1t, 2048, 1024, b1, T,
        nullptr, nullptr, nullptr, nullptr, nullptr, nullptr, nullptr);
    gemm128<EPI_RK4, 2><<<dim3(4, MB), blk, 0, stream>>>(T, 2048, w2t, 1024, 2048, b2, hs,
        h0b, state, kacc, out, xh + 256, nullptr, nullptr);

    gemm128<EPI_TANH, 0><<<dim3(8, MB), blk, 0, stream>>>(hs, 1024, w1t, 2048, 1024, b1, T,
        nullptr, nullptr, nullptr, nullptr, nullptr, nullptr, nullptr);
    gemm128<EPI_RK4, 3><<<dim3(4, MB), blk, 0, stream>>>(T, 2048, w2t, 1024, 2048, b2, hs,
        h0b, state, kacc, out, xh + 256, nullptr, nullptr);

    // ---- GRU ----
    // r,z gates: [x|ht_] (K=1280) @ wrz^T -> sigmoid -> T (B x 2048 bf16)
    gemm128<EPI_SIG, 0><<<dim3(8, MB), blk, 0, stream>>>(xh, 1280, wrz, 2048, 1280, brz, T,
        nullptr, nullptr, nullptr, nullptr, nullptr, nullptr, nullptr);
    // i_n: x (K=256) @ Wih_n^T + bih_n -> bf16 (into h0b space, h0b dead now)
    gemm128<EPI_BIASBF, 0><<<dim3(4, MB), blk, 0, stream>>>(xh, 1280, win, 1024, 256,
        bih + 2048, inbf, nullptr, nullptr, nullptr, nullptr, nullptr, nullptr, nullptr);
    // h_n GEMM + full GRU merge -> out[:, 16:]
    gemm128<EPI_FIN, 0><<<dim3(4, MB), blk, 0, stream>>>(xh + 256, 1280, whn, 1024, 1024,
        bhh + 2048, nullptr, nullptr, nullptr, nullptr, out, xh + 256, T, inbf);

    // ---- readout out[:, :16] ----
    k_ly<<<(B * 16) / 256, 256, 0, stream>>>(out, state, Wly, bly, y_type, out, B);
}